// Round 2
// baseline (20911.681 us; speedup 1.0000x reference)
//
#include <hip/hip_runtime.h>

#define BATCH 65536
#define DIN   256
#define DHID  512
#define BM    64
#define APAD  264   // 256+8 shorts -> 528B row stride, 16B-aligned, 2-way bank alias (free)
#define HPAD  136   // 128+8 shorts -> 272B
#define NSTEPS 8

typedef __attribute__((ext_vector_type(8))) short short8;
typedef __attribute__((ext_vector_type(4))) float f32x4;

__device__ __forceinline__ unsigned short f2bf(float f){
  union { float f; unsigned u; } v; v.f = f;
  unsigned u = v.u;
  unsigned r = (u + 0x7FFFu + ((u >> 16) & 1u)) >> 16;   // RN-even
  return (unsigned short)r;
}
__device__ __forceinline__ float bf2f(unsigned short h){
  union { float f; unsigned u; } v; v.u = ((unsigned)h) << 16; return v.f;
}
__device__ __forceinline__ float tanh_fast(float x){
  float e = __expf(2.0f * x);
  return 1.0f - 2.0f / (e + 1.0f);
}

// W1[256][512] -> W1T hi/lo [512][256]; W2[512][256] -> W2T hi/lo [256][512].
__global__ void prep_weights(const float* __restrict__ W1, const float* __restrict__ W2,
                             unsigned short* __restrict__ W1h, unsigned short* __restrict__ W1l,
                             unsigned short* __restrict__ W2h, unsigned short* __restrict__ W2l){
  int idx = blockIdx.x * blockDim.x + threadIdx.x;
  if (idx >= DIN * DHID) return;
  {
    int k = idx / DHID, n = idx % DHID;
    float v = W1[idx];
    unsigned short h = f2bf(v);
    W1h[n * DIN + k] = h;
    W1l[n * DIN + k] = f2bf(v - bf2f(h));
  }
  {
    int k = idx / DIN, n = idx % DIN;
    float v = W2[idx];
    unsigned short h = f2bf(v);
    W2h[n * DHID + k] = h;
    W2l[n * DHID + k] = f2bf(v - bf2f(h));
  }
}

// One persistent kernel: each block owns 64 rows and integrates them through
// all 8 RK4 steps (32 f-evals). State (y, RK4 accumulator, stage output F)
// lives in registers in the MFMA C-layout; the stage input is re-staged
// regs->LDS as a bf16 A-tile each eval. Weights (1 MB, split hi/lo) stream
// from L2. No global state traffic between evals.
__global__ __launch_bounds__(512, 2)
void ode_all(const float* __restrict__ x, float* __restrict__ out,
             const unsigned short* __restrict__ W1h, const unsigned short* __restrict__ W1l,
             const unsigned short* __restrict__ W2h, const unsigned short* __restrict__ W2l,
             const float* __restrict__ b1, const float* __restrict__ b2)
{
  __shared__ unsigned short Ash[BM * APAD];   // 33.8 KB
  __shared__ unsigned short Hsh[BM * HPAD];   // 17.4 KB

  const int tid  = threadIdx.x;
  const int lane = tid & 63;
  const int wid  = tid >> 6;     // 0..7
  const int wr   = wid >> 1;     // 0..3 : 16-row slice
  const int wc   = wid & 1;      // 0..1 : 128-col slice
  const int l15  = lane & 15;
  const int l4   = lane >> 4;    // 0..3
  const size_t r0 = (size_t)blockIdx.x * BM;

  // ---- preload biases into registers ----
  float b1v[4][4];
  #pragma unroll
  for (int ch = 0; ch < 4; ++ch)
    #pragma unroll
    for (int nt = 0; nt < 4; ++nt)
      b1v[ch][nt] = b1[ch * 128 + wc * 64 + nt * 16 + l15];
  float b2v[8];
  #pragma unroll
  for (int nt = 0; nt < 8; ++nt)
    b2v[nt] = b2[wc * 128 + nt * 16 + l15];

  // ---- load y in C-layout: row = wr*16 + l4*4 + r, col = wc*128 + nt*16 + l15 ----
  float y[8][4], A[8][4];
  f32x4 F[8];
  #pragma unroll
  for (int nt = 0; nt < 8; ++nt)
    #pragma unroll
    for (int r = 0; r < 4; ++r)
      y[nt][r] = x[(r0 + wr * 16 + l4 * 4 + r) * DIN + wc * 128 + nt * 16 + l15];

  const float h  = 1.0f / (float)NSTEPS;
  const int arow = wr * 16 + l15;

  for (int s = 0; s < NSTEPS; ++s){
    #pragma unroll 1
    for (int st = 0; st < 4; ++st){
      // ---- stage input X -> Ash (bf16). X: st0:y  st1/2:y+(h/2)F  st3:y+h*F ----
      const float cX = (st == 0) ? 0.0f : (st == 3 ? h : 0.5f * h);
      #pragma unroll
      for (int nt = 0; nt < 8; ++nt){
        #pragma unroll
        for (int r = 0; r < 4; ++r){
          float xv = (st == 0) ? y[nt][r] : y[nt][r] + cX * (F[nt][r] + b2v[nt]);
          Ash[(wr * 16 + l4 * 4 + r) * APAD + wc * 128 + nt * 16 + l15] = f2bf(xv);
        }
      }
      __syncthreads();

      #pragma unroll
      for (int i = 0; i < 8; ++i) F[i] = (f32x4){0.f, 0.f, 0.f, 0.f};

      for (int ch = 0; ch < 4; ++ch){
        // ---- GEMM1 chunk: U = X * W1[:, ch*128 + wc*64 .. +64] (2-term: W split) ----
        f32x4 acc1[4];
        #pragma unroll
        for (int i = 0; i < 4; ++i) acc1[i] = (f32x4){0.f, 0.f, 0.f, 0.f};

        #pragma unroll
        for (int ks = 0; ks < 8; ++ks){
          short8 af = *reinterpret_cast<const short8*>(&Ash[arow * APAD + ks * 32 + l4 * 8]);
          #pragma unroll
          for (int nt = 0; nt < 4; ++nt){
            int ncol = ch * 128 + wc * 64 + nt * 16 + l15;
            int boff = ncol * DIN + ks * 32 + l4 * 8;
            short8 bh = *reinterpret_cast<const short8*>(W1h + boff);
            short8 bl = *reinterpret_cast<const short8*>(W1l + boff);
            acc1[nt] = __builtin_amdgcn_mfma_f32_16x16x32_bf16(af, bh, acc1[nt], 0, 0, 0);
            acc1[nt] = __builtin_amdgcn_mfma_f32_16x16x32_bf16(af, bl, acc1[nt], 0, 0, 0);
          }
        }

        __syncthreads();   // previous chunk's Hsh readers done
        // ---- bias + tanh -> H chunk (plain bf16) ----
        #pragma unroll
        for (int nt = 0; nt < 4; ++nt){
          int colL = wc * 64 + nt * 16 + l15;
          #pragma unroll
          for (int r = 0; r < 4; ++r){
            float t = tanh_fast(acc1[nt][r] + b1v[ch][nt]);
            Hsh[(wr * 16 + l4 * 4 + r) * HPAD + colL] = f2bf(t);
          }
        }
        __syncthreads();

        // ---- GEMM2 partial: F += H_chunk * W2[ch*128.. , :] (2-term: W split) ----
        #pragma unroll
        for (int ks = 0; ks < 4; ++ks){
          short8 hf = *reinterpret_cast<const short8*>(&Hsh[arow * HPAD + ks * 32 + l4 * 8]);
          #pragma unroll
          for (int nt = 0; nt < 8; ++nt){
            int ncol = wc * 128 + nt * 16 + l15;
            int boff = ncol * DHID + ch * 128 + ks * 32 + l4 * 8;
            short8 bh = *reinterpret_cast<const short8*>(W2h + boff);
            short8 bl = *reinterpret_cast<const short8*>(W2l + boff);
            F[nt] = __builtin_amdgcn_mfma_f32_16x16x32_bf16(hf, bh, F[nt], 0, 0, 0);
            F[nt] = __builtin_amdgcn_mfma_f32_16x16x32_bf16(hf, bl, F[nt], 0, 0, 0);
          }
        }
      }

      // ---- RK4 state update (F+b2v = k_st) ----
      if (st == 0){
        #pragma unroll
        for (int nt = 0; nt < 8; ++nt)
          #pragma unroll
          for (int r = 0; r < 4; ++r)
            A[nt][r] = y[nt][r] + (h / 6.0f) * (F[nt][r] + b2v[nt]);
      } else if (st == 1 || st == 2){
        #pragma unroll
        for (int nt = 0; nt < 8; ++nt)
          #pragma unroll
          for (int r = 0; r < 4; ++r)
            A[nt][r] += (h / 3.0f) * (F[nt][r] + b2v[nt]);
      } else {
        #pragma unroll
        for (int nt = 0; nt < 8; ++nt)
          #pragma unroll
          for (int r = 0; r < 4; ++r)
            y[nt][r] = A[nt][r] + (h / 6.0f) * (F[nt][r] + b2v[nt]);
      }
      // next stage's Ash writes are safe: all Ash reads of this stage finished
      // before the pre-H-write barrier of chunk 3; GEMM2 only touches Hsh/W.
    }
  }

  // ---- write final state ----
  #pragma unroll
  for (int nt = 0; nt < 8; ++nt)
    #pragma unroll
    for (int r = 0; r < 4; ++r)
      out[(r0 + wr * 16 + l4 * 4 + r) * DIN + wc * 128 + nt * 16 + l15] = y[nt][r];
}

extern "C" void kernel_launch(void* const* d_in, const int* in_sizes, int n_in,
                              void* d_out, int out_size, void* d_ws, size_t ws_size,
                              hipStream_t stream)
{
  const float* x  = (const float*)d_in[0];
  const float* W1 = (const float*)d_in[1];
  const float* b1 = (const float*)d_in[2];
  const float* W2 = (const float*)d_in[3];
  const float* b2 = (const float*)d_in[4];
  float* out = (float*)d_out;

  unsigned short* W1h = (unsigned short*)d_ws;
  unsigned short* W1l = W1h + DIN * DHID;
  unsigned short* W2h = W1l + DIN * DHID;
  unsigned short* W2l = W2h + DIN * DHID;   // 1 MiB total

  prep_weights<<<512, 256, 0, stream>>>(W1, W2, W1h, W1l, W2h, W2l);
  ode_all<<<BATCH / BM, 512, 0, stream>>>(x, out, W1h, W1l, W2h, W2l, b1, b2);
}